// Round 9
// baseline (4168.278 us; speedup 1.0000x reference)
//
#include <hip/hip_runtime.h>
#include <math.h>

#define Hh  8
#define Dd  512
#define SUB 256          // D/2
#define Nk  1024         // num_subkeys
#define TK  32           // top_k
#define Rr  8            // rows (b,c) per block
#define NT  256
#define W_ELEMS (65536 * 32)

// Phase-1 arithmetic: single accumulator per (row,key), strictly sequential
// FUSED-FMA chain over the contraction dim in natural order (d = 0..255) —
// bit-identical to all previous rounds. Selection sets and tie-breaks
// (lowest flat index, XLA semantics) also identical.
//
// R9 latency round (R8 semantics preserved):
//  - qs restaged PER SIDE as [8][256] (8 KB): LDS 36.8 -> 28 KB
//    => 5 blocks/CU (20 waves/CU), was 4.
//  - k double-buffered: idx+1's 4 float4s issued before idx's 128 FMAs
//    (load->use distance ~1 iteration > L2 latency). Safe now that the
//    rule-#20 scratch demotion is gone (batch loop fully unrolled).
//  - local argmax = depth-4 tournament tree (contiguous pairs, strict '>'
//    prefers left => lowest index on ties preserved exactly); serial chain
//    ~120 -> ~32 cyc per selection iteration.

__device__ __forceinline__ float wave_fmax_bcast(float x) {
    // classic gfx9 DPP max-reduce; result broadcast via readlane(63).
    int v;
    v = __builtin_amdgcn_update_dpp(0xff800000, __float_as_int(x), 0x111, 0xf, 0xf, false);
    x = fmaxf(x, __int_as_float(v));   // row_shr:1
    v = __builtin_amdgcn_update_dpp(0xff800000, __float_as_int(x), 0x112, 0xf, 0xf, false);
    x = fmaxf(x, __int_as_float(v));   // row_shr:2
    v = __builtin_amdgcn_update_dpp(0xff800000, __float_as_int(x), 0x114, 0xf, 0xf, false);
    x = fmaxf(x, __int_as_float(v));   // row_shr:4
    v = __builtin_amdgcn_update_dpp(0xff800000, __float_as_int(x), 0x118, 0xf, 0xf, false);
    x = fmaxf(x, __int_as_float(v));   // row_shr:8  -> lane15 of each row16 = row max
    v = __builtin_amdgcn_update_dpp(0xff800000, __float_as_int(x), 0x142, 0xa, 0xf, false);
    x = fmaxf(x, __int_as_float(v));   // row_bcast:15
    v = __builtin_amdgcn_update_dpp(0xff800000, __float_as_int(x), 0x143, 0xc, 0xf, false);
    x = fmaxf(x, __int_as_float(v));   // row_bcast:31 -> lane 63 = wave max
    return __int_as_float(__builtin_amdgcn_readlane(__float_as_int(x), 63));
}

// depth-4 tournament argmax over 16 registers; tie -> lowest index.
// (contiguous pairing: left subtree indices always < right => strict '>'
//  preferring left reproduces the sequential lowest-index-on-ties scan)
__device__ __forceinline__ void argmax16(const float v[16], float& lv, int& li) {
    float w1[8]; int j1[8];
    #pragma unroll
    for (int i = 0; i < 8; ++i) {
        const bool g = v[2*i+1] > v[2*i];
        w1[i] = g ? v[2*i+1] : v[2*i];
        j1[i] = g ? 2*i+1 : 2*i;
    }
    float w2[4]; int j2[4];
    #pragma unroll
    for (int i = 0; i < 4; ++i) {
        const bool g = w1[2*i+1] > w1[2*i];
        w2[i] = g ? w1[2*i+1] : w1[2*i];
        j2[i] = g ? j1[2*i+1] : j1[2*i];
    }
    float w3[2]; int j3[2];
    #pragma unroll
    for (int i = 0; i < 2; ++i) {
        const bool g = w2[2*i+1] > w2[2*i];
        w3[i] = g ? w2[2*i+1] : w2[2*i];
        j3[i] = g ? j2[2*i+1] : j2[2*i];
    }
    const bool g = w3[1] > w3[0];
    lv = g ? w3[1] : w3[0];
    li = g ? j3[1] : j3[0];
}

__global__ __launch_bounds__(NT, 2)
void pk_kernel(const float* __restrict__ query,
               const float* __restrict__ keyl,
               const float* __restrict__ keyr,
               float* __restrict__ out)
{
    __shared__ __attribute__((aligned(16))) float qs[Rr][SUB];     //  8 KB (per-side)
    __shared__ __attribute__((aligned(16))) float sc[4][Nk];       // 16 KB (swizzled)
    __shared__ __attribute__((aligned(16))) float topv[2][Rr][TK]; //  2 KB
    __shared__ __attribute__((aligned(16))) int   topi[2][Rr][TK]; //  2 KB

    const int bid  = blockIdx.x;
    const int h    = bid >> 10;           // h-major for L2 key locality
    const int tile = bid & 1023;
    const int bc0  = tile * Rr;
    const int t    = threadIdx.x;
    const int lane = t & 63;
    const int wave = t >> 6;

    const int X = ((t >> 4) & 7) << 2;    // store-swizzle for this thread

    for (int side = 0; side < 2; ++side) {
        // ---- stage this side's q slice to LDS, fully coalesced ----
        {
            const int r0 = wave * 2;
            const float4* s0 = (const float4*)(query +
                ((size_t)(bc0 + r0) * Hh + h) * Dd + side * SUB);
            const float4* s1 = (const float4*)(query +
                ((size_t)(bc0 + r0 + 1) * Hh + h) * Dd + side * SUB);
            ((float4*)qs[r0])[lane]     = s0[lane];
            ((float4*)qs[r0 + 1])[lane] = s1[lane];
        }
        __syncthreads();

        const float* kbase = (side == 0 ? keyl : keyr) + (size_t)h * Nk * SUB;
        const float4* kr0 = (const float4*)(kbase + (size_t)(0 * 256 + t) * SUB);
        const float4* kr1 = (const float4*)(kbase + (size_t)(1 * 256 + t) * SUB);
        const float4* kr2 = (const float4*)(kbase + (size_t)(2 * 256 + t) * SUB);
        const float4* kr3 = (const float4*)(kbase + (size_t)(3 * 256 + t) * SUB);

        float acc[Rr][4];
        #pragma unroll
        for (int r = 0; r < Rr; ++r)
            #pragma unroll
            for (int g = 0; g < 4; ++g) acc[r][g] = 0.0f;

        // ---- phase 1: k double-buffered; q broadcast from LDS ----
        float4 kc0 = kr0[0], kc1 = kr1[0], kc2 = kr2[0], kc3 = kr3[0];
        #pragma unroll 1
        for (int idx = 0; idx < 64; ++idx) {
            const int nx = (idx + 1) & 63;            // wrap: last prefetch unused
            float4 kn0 = kr0[nx], kn1 = kr1[nx], kn2 = kr2[nx], kn3 = kr3[nx];
            #pragma unroll
            for (int r = 0; r < Rr; ++r) {
                float4 qv = ((const float4*)qs[r])[idx];   // broadcast ds_read_b128
                acc[r][0] = fmaf(qv.x, kc0.x, acc[r][0]);
                acc[r][1] = fmaf(qv.x, kc1.x, acc[r][1]);
                acc[r][2] = fmaf(qv.x, kc2.x, acc[r][2]);
                acc[r][3] = fmaf(qv.x, kc3.x, acc[r][3]);
                acc[r][0] = fmaf(qv.y, kc0.y, acc[r][0]);
                acc[r][1] = fmaf(qv.y, kc1.y, acc[r][1]);
                acc[r][2] = fmaf(qv.y, kc2.y, acc[r][2]);
                acc[r][3] = fmaf(qv.y, kc3.y, acc[r][3]);
                acc[r][0] = fmaf(qv.z, kc0.z, acc[r][0]);
                acc[r][1] = fmaf(qv.z, kc1.z, acc[r][1]);
                acc[r][2] = fmaf(qv.z, kc2.z, acc[r][2]);
                acc[r][3] = fmaf(qv.z, kc3.z, acc[r][3]);
                acc[r][0] = fmaf(qv.w, kc0.w, acc[r][0]);
                acc[r][1] = fmaf(qv.w, kc1.w, acc[r][1]);
                acc[r][2] = fmaf(qv.w, kc2.w, acc[r][2]);
                acc[r][3] = fmaf(qv.w, kc3.w, acc[r][3]);
            }
            kc0 = kn0; kc1 = kn1; kc2 = kn2; kc3 = kn3;
        }

        // ---- phase 2: two batches of 4 rows; one row per wave ----
        // batch loop FULLY UNROLLED (rule #20: acc indices must be static)
        #pragma unroll
        for (int batch = 0; batch < 2; ++batch) {
            // swizzled store: element k = g*256+t -> column k ^ (((k>>4)&7)<<2)
            #pragma unroll
            for (int rr = 0; rr < 4; ++rr)
                #pragma unroll
                for (int g = 0; g < 4; ++g)
                    sc[rr][g * 256 + (t ^ X)] = acc[batch * 4 + rr][g];
            __syncthreads();

            const int r = batch * 4 + wave;       // actual row this wave selects
            float v[16];
            const float4* sp = (const float4*)sc[wave];
            #pragma unroll
            for (int c = 0; c < 4; ++c) {
                const int gidx = (4 * lane + c) ^ (lane & 7);   // swizzled granule
                float4 x = sp[gidx];
                v[4*c+0] = x.x; v[4*c+1] = x.y; v[4*c+2] = x.z; v[4*c+3] = x.w;
            }
            for (int it = 0; it < TK; ++it) {
                float lv; int li;
                argmax16(v, lv, li);
                float M = wave_fmax_bcast(lv);
                const int w = (int)__builtin_ctzll(__ballot(lv == M)); // lowest lane = lowest pos
                if (lane == w) { topv[side][r][it] = M; topi[side][r][it] = (lane << 4) | li; }
                const bool kk = (lane == w);
                #pragma unroll
                for (int i = 0; i < 16; ++i)                 // static-index elimination
                    v[i] = (kk && i == li) ? -INFINITY : v[i];
            }
            __syncthreads();
        }
    }

    // ---- phase 3: 32x32 product sums, top-32, softmax; lane owns p in [16l,16l+16) ----
    {
        const int ra = wave, rb = wave + 4;
        float va[16], vb[16];
        // p = 16*lane + i ; a = p>>5 = lane>>1 ; b = p&31 = 16*(lane&1)+i
        const float tla = topv[0][ra][lane >> 1];
        const float tlb = topv[0][rb][lane >> 1];
        const float4* t1a = (const float4*)topv[1][ra];
        const float4* t1b = (const float4*)topv[1][rb];
        #pragma unroll
        for (int c = 0; c < 4; ++c) {
            float4 xa = t1a[4 * (lane & 1) + c];
            float4 xb = t1b[4 * (lane & 1) + c];
            va[4*c+0] = __fadd_rn(tla, xa.x); va[4*c+1] = __fadd_rn(tla, xa.y);
            va[4*c+2] = __fadd_rn(tla, xa.z); va[4*c+3] = __fadd_rn(tla, xa.w);
            vb[4*c+0] = __fadd_rn(tlb, xb.x); vb[4*c+1] = __fadd_rn(tlb, xb.y);
            vb[4*c+2] = __fadd_rn(tlb, xb.z); vb[4*c+3] = __fadd_rn(tlb, xb.w);
        }
        float m0a = 0.0f, wva = 0.0f; int wpa = 0;
        float m0b = 0.0f, wvb = 0.0f; int wpb = 0;
        for (int it = 0; it < TK; ++it) {
            float la, lb; int ia_, ib_;
            argmax16(va, la, ia_);
            argmax16(vb, lb, ib_);
            float Ma = wave_fmax_bcast(la);
            float Mb = wave_fmax_bcast(lb);
            const int wa = (int)__builtin_ctzll(__ballot(la == Ma));
            const int wb = (int)__builtin_ctzll(__ballot(lb == Mb));
            const int pa = (wa << 4) | __builtin_amdgcn_readlane(ia_, wa);  // uniform
            const int pb = (wb << 4) | __builtin_amdgcn_readlane(ib_, wb);
            if (it == 0) { m0a = Ma; m0b = Mb; }          // rank 0 = max
            if (lane == it) { wva = Ma; wpa = pa; wvb = Mb; wpb = pb; }
            const bool ka = (lane == wa), kb = (lane == wb);
            #pragma unroll
            for (int i = 0; i < 16; ++i) {
                va[i] = (ka && i == ia_) ? -INFINITY : va[i];
                vb[i] = (kb && i == ib_) ? -INFINITY : vb[i];
            }
        }
        float ea = (lane < TK) ? expf(wva - m0a) : 0.0f;
        float eb = (lane < TK) ? expf(wvb - m0b) : 0.0f;
        float sa = ea, sb = eb;
        #pragma unroll
        for (int m = 1; m < 64; m <<= 1) {
            sa += __shfl_xor(sa, m, 64);
            sb += __shfl_xor(sb, m, 64);
        }
        if (lane < TK) {
            {
                const int bc = bc0 + ra;
                const size_t base = ((size_t)bc * Hh + h) * TK;
                const int a = wpa >> 5;
                // reference quirk: product_indices[a*32+b] = l[a]*N + r[a]
                const int fl = topi[0][ra][a] * Nk + topi[1][ra][a];
                out[base + lane] = ea / sa;
                out[(size_t)W_ELEMS + base + lane] = (float)fl;
            }
            {
                const int bc = bc0 + rb;
                const size_t base = ((size_t)bc * Hh + h) * TK;
                const int a = wpb >> 5;
                const int fl = topi[0][rb][a] * Nk + topi[1][rb][a];
                out[base + lane] = eb / sb;
                out[(size_t)W_ELEMS + base + lane] = (float)fl;
            }
        }
    }
}

extern "C" void kernel_launch(void* const* d_in, const int* in_sizes, int n_in,
                              void* d_out, int out_size, void* d_ws, size_t ws_size,
                              hipStream_t stream)
{
    const float* query = (const float*)d_in[0];
    const float* keyl  = (const float*)d_in[1];
    const float* keyr  = (const float*)d_in[2];
    float* out = (float*)d_out;
    pk_kernel<<<dim3(8192), dim3(NT), 0, stream>>>(query, keyl, keyr, out);
}

// Round 10
// 3853.802 us; speedup vs baseline: 1.0816x; 1.0816x over previous
//
#include <hip/hip_runtime.h>
#include <math.h>

#define Hh  8
#define Dd  512
#define SUB 256          // D/2
#define Nk  1024         // num_subkeys
#define TK  32           // top_k
#define Rr  8            // rows (b,c) per block
#define NT  256
#define W_ELEMS (65536 * 32)

// Phase-1 arithmetic: single accumulator per (row,key), strictly sequential
// FUSED-FMA chain over the contraction dim in natural order (d = 0..255) —
// bit-identical to all previous rounds. Selection sets and tie-breaks
// (lowest flat index, XLA semantics) also identical.
//
// R10 = R8's PROVEN phase-1 loop structure (js outer / c inner unroll-4:
// 512-FMA straight-line blocks the compiler pipelines itself — R9's manual
// double-buffer + single-idx body collapsed VGPR to 44 and serialized every
// load; common-mistake #5) + R9's two good pieces:
//   - per-side qs[8][256] (LDS 28 KB -> 5 blocks/CU, 20 waves)
//   - argmax16 tournament (depth-4 vs depth-15 chain) in phases 2/3

__device__ __forceinline__ float wave_fmax_bcast(float x) {
    // classic gfx9 DPP max-reduce; result broadcast via readlane(63).
    int v;
    v = __builtin_amdgcn_update_dpp(0xff800000, __float_as_int(x), 0x111, 0xf, 0xf, false);
    x = fmaxf(x, __int_as_float(v));   // row_shr:1
    v = __builtin_amdgcn_update_dpp(0xff800000, __float_as_int(x), 0x112, 0xf, 0xf, false);
    x = fmaxf(x, __int_as_float(v));   // row_shr:2
    v = __builtin_amdgcn_update_dpp(0xff800000, __float_as_int(x), 0x114, 0xf, 0xf, false);
    x = fmaxf(x, __int_as_float(v));   // row_shr:4
    v = __builtin_amdgcn_update_dpp(0xff800000, __float_as_int(x), 0x118, 0xf, 0xf, false);
    x = fmaxf(x, __int_as_float(v));   // row_shr:8  -> lane15 of each row16 = row max
    v = __builtin_amdgcn_update_dpp(0xff800000, __float_as_int(x), 0x142, 0xa, 0xf, false);
    x = fmaxf(x, __int_as_float(v));   // row_bcast:15
    v = __builtin_amdgcn_update_dpp(0xff800000, __float_as_int(x), 0x143, 0xc, 0xf, false);
    x = fmaxf(x, __int_as_float(v));   // row_bcast:31 -> lane 63 = wave max
    return __int_as_float(__builtin_amdgcn_readlane(__float_as_int(x), 63));
}

// depth-4 tournament argmax over 16 registers; tie -> lowest index.
// (contiguous pairing: left subtree indices always < right => strict '>'
//  preferring left reproduces the sequential lowest-index-on-ties scan)
__device__ __forceinline__ void argmax16(const float v[16], float& lv, int& li) {
    float w1[8]; int j1[8];
    #pragma unroll
    for (int i = 0; i < 8; ++i) {
        const bool g = v[2*i+1] > v[2*i];
        w1[i] = g ? v[2*i+1] : v[2*i];
        j1[i] = g ? 2*i+1 : 2*i;
    }
    float w2[4]; int j2[4];
    #pragma unroll
    for (int i = 0; i < 4; ++i) {
        const bool g = w1[2*i+1] > w1[2*i];
        w2[i] = g ? w1[2*i+1] : w1[2*i];
        j2[i] = g ? j1[2*i+1] : j1[2*i];
    }
    float w3[2]; int j3[2];
    #pragma unroll
    for (int i = 0; i < 2; ++i) {
        const bool g = w2[2*i+1] > w2[2*i];
        w3[i] = g ? w2[2*i+1] : w2[2*i];
        j3[i] = g ? j2[2*i+1] : j2[2*i];
    }
    const bool g = w3[1] > w3[0];
    lv = g ? w3[1] : w3[0];
    li = g ? j3[1] : j3[0];
}

__global__ __launch_bounds__(NT, 2)
void pk_kernel(const float* __restrict__ query,
               const float* __restrict__ keyl,
               const float* __restrict__ keyr,
               float* __restrict__ out)
{
    __shared__ __attribute__((aligned(16))) float qs[Rr][SUB];     //  8 KB (per-side)
    __shared__ __attribute__((aligned(16))) float sc[4][Nk];       // 16 KB (swizzled)
    __shared__ __attribute__((aligned(16))) float topv[2][Rr][TK]; //  2 KB
    __shared__ __attribute__((aligned(16))) int   topi[2][Rr][TK]; //  2 KB

    const int bid  = blockIdx.x;
    const int h    = bid >> 10;           // h-major for L2 key locality
    const int tile = bid & 1023;
    const int bc0  = tile * Rr;
    const int t    = threadIdx.x;
    const int lane = t & 63;
    const int wave = t >> 6;

    const int X = ((t >> 4) & 7) << 2;    // store-swizzle for this thread

    for (int side = 0; side < 2; ++side) {
        // ---- stage this side's q slice to LDS, fully coalesced ----
        {
            const int r0 = wave * 2;
            const float4* s0 = (const float4*)(query +
                ((size_t)(bc0 + r0) * Hh + h) * Dd + side * SUB);
            const float4* s1 = (const float4*)(query +
                ((size_t)(bc0 + r0 + 1) * Hh + h) * Dd + side * SUB);
            ((float4*)qs[r0])[lane]     = s0[lane];
            ((float4*)qs[r0 + 1])[lane] = s1[lane];
        }
        __syncthreads();

        const float* kbase = (side == 0 ? keyl : keyr) + (size_t)h * Nk * SUB;
        const float4* kr0 = (const float4*)(kbase + (size_t)(0 * 256 + t) * SUB);
        const float4* kr1 = (const float4*)(kbase + (size_t)(1 * 256 + t) * SUB);
        const float4* kr2 = (const float4*)(kbase + (size_t)(2 * 256 + t) * SUB);
        const float4* kr3 = (const float4*)(kbase + (size_t)(3 * 256 + t) * SUB);

        float acc[Rr][4];
        #pragma unroll
        for (int r = 0; r < Rr; ++r)
            #pragma unroll
            for (int g = 0; g < 4; ++g) acc[r][g] = 0.0f;

        // ---- phase 1: R8's proven structure — js outer, c inner unroll-4,
        //      q broadcast from LDS once per (idx,row), 4 keys/thread ----
        #pragma unroll 1
        for (int js = 0; js < 16; ++js) {
            #pragma unroll
            for (int c = 0; c < 4; ++c) {
                const int idx = 4 * js + c;
                float4 k0 = kr0[idx], k1 = kr1[idx], k2 = kr2[idx], k3 = kr3[idx];
                #pragma unroll
                for (int r = 0; r < Rr; ++r) {
                    float4 qv = ((const float4*)qs[r])[idx];   // broadcast ds_read_b128
                    acc[r][0] = fmaf(qv.x, k0.x, acc[r][0]);
                    acc[r][1] = fmaf(qv.x, k1.x, acc[r][1]);
                    acc[r][2] = fmaf(qv.x, k2.x, acc[r][2]);
                    acc[r][3] = fmaf(qv.x, k3.x, acc[r][3]);
                    acc[r][0] = fmaf(qv.y, k0.y, acc[r][0]);
                    acc[r][1] = fmaf(qv.y, k1.y, acc[r][1]);
                    acc[r][2] = fmaf(qv.y, k2.y, acc[r][2]);
                    acc[r][3] = fmaf(qv.y, k3.y, acc[r][3]);
                    acc[r][0] = fmaf(qv.z, k0.z, acc[r][0]);
                    acc[r][1] = fmaf(qv.z, k1.z, acc[r][1]);
                    acc[r][2] = fmaf(qv.z, k2.z, acc[r][2]);
                    acc[r][3] = fmaf(qv.z, k3.z, acc[r][3]);
                    acc[r][0] = fmaf(qv.w, k0.w, acc[r][0]);
                    acc[r][1] = fmaf(qv.w, k1.w, acc[r][1]);
                    acc[r][2] = fmaf(qv.w, k2.w, acc[r][2]);
                    acc[r][3] = fmaf(qv.w, k3.w, acc[r][3]);
                }
            }
        }

        // ---- phase 2: two batches of 4 rows; one row per wave ----
        // batch loop FULLY UNROLLED (rule #20: acc indices must be static)
        #pragma unroll
        for (int batch = 0; batch < 2; ++batch) {
            // swizzled store: element k = g*256+t -> column k ^ (((k>>4)&7)<<2)
            #pragma unroll
            for (int rr = 0; rr < 4; ++rr)
                #pragma unroll
                for (int g = 0; g < 4; ++g)
                    sc[rr][g * 256 + (t ^ X)] = acc[batch * 4 + rr][g];
            __syncthreads();

            const int r = batch * 4 + wave;       // actual row this wave selects
            float v[16];
            const float4* sp = (const float4*)sc[wave];
            #pragma unroll
            for (int c = 0; c < 4; ++c) {
                const int gidx = (4 * lane + c) ^ (lane & 7);   // swizzled granule
                float4 x = sp[gidx];
                v[4*c+0] = x.x; v[4*c+1] = x.y; v[4*c+2] = x.z; v[4*c+3] = x.w;
            }
            for (int it = 0; it < TK; ++it) {
                float lv; int li;
                argmax16(v, lv, li);
                float M = wave_fmax_bcast(lv);
                const int w = (int)__builtin_ctzll(__ballot(lv == M)); // lowest lane = lowest pos
                if (lane == w) { topv[side][r][it] = M; topi[side][r][it] = (lane << 4) | li; }
                const bool kk = (lane == w);
                #pragma unroll
                for (int i = 0; i < 16; ++i)                 // static-index elimination
                    v[i] = (kk && i == li) ? -INFINITY : v[i];
            }
            __syncthreads();
        }
    }

    // ---- phase 3: 32x32 product sums, top-32, softmax; lane owns p in [16l,16l+16) ----
    {
        const int ra = wave, rb = wave + 4;
        float va[16], vb[16];
        // p = 16*lane + i ; a = p>>5 = lane>>1 ; b = p&31 = 16*(lane&1)+i
        const float tla = topv[0][ra][lane >> 1];
        const float tlb = topv[0][rb][lane >> 1];
        const float4* t1a = (const float4*)topv[1][ra];
        const float4* t1b = (const float4*)topv[1][rb];
        #pragma unroll
        for (int c = 0; c < 4; ++c) {
            float4 xa = t1a[4 * (lane & 1) + c];
            float4 xb = t1b[4 * (lane & 1) + c];
            va[4*c+0] = __fadd_rn(tla, xa.x); va[4*c+1] = __fadd_rn(tla, xa.y);
            va[4*c+2] = __fadd_rn(tla, xa.z); va[4*c+3] = __fadd_rn(tla, xa.w);
            vb[4*c+0] = __fadd_rn(tlb, xb.x); vb[4*c+1] = __fadd_rn(tlb, xb.y);
            vb[4*c+2] = __fadd_rn(tlb, xb.z); vb[4*c+3] = __fadd_rn(tlb, xb.w);
        }
        float m0a = 0.0f, wva = 0.0f; int wpa = 0;
        float m0b = 0.0f, wvb = 0.0f; int wpb = 0;
        for (int it = 0; it < TK; ++it) {
            float la, lb; int ia_, ib_;
            argmax16(va, la, ia_);
            argmax16(vb, lb, ib_);
            float Ma = wave_fmax_bcast(la);
            float Mb = wave_fmax_bcast(lb);
            const int wa = (int)__builtin_ctzll(__ballot(la == Ma));
            const int wb = (int)__builtin_ctzll(__ballot(lb == Mb));
            const int pa = (wa << 4) | __builtin_amdgcn_readlane(ia_, wa);  // uniform
            const int pb = (wb << 4) | __builtin_amdgcn_readlane(ib_, wb);
            if (it == 0) { m0a = Ma; m0b = Mb; }          // rank 0 = max
            if (lane == it) { wva = Ma; wpa = pa; wvb = Mb; wpb = pb; }
            const bool ka = (lane == wa), kb = (lane == wb);
            #pragma unroll
            for (int i = 0; i < 16; ++i) {
                va[i] = (ka && i == ia_) ? -INFINITY : va[i];
                vb[i] = (kb && i == ib_) ? -INFINITY : vb[i];
            }
        }
        float ea = (lane < TK) ? expf(wva - m0a) : 0.0f;
        float eb = (lane < TK) ? expf(wvb - m0b) : 0.0f;
        float sa = ea, sb = eb;
        #pragma unroll
        for (int m = 1; m < 64; m <<= 1) {
            sa += __shfl_xor(sa, m, 64);
            sb += __shfl_xor(sb, m, 64);
        }
        if (lane < TK) {
            {
                const int bc = bc0 + ra;
                const size_t base = ((size_t)bc * Hh + h) * TK;
                const int a = wpa >> 5;
                // reference quirk: product_indices[a*32+b] = l[a]*N + r[a]
                const int fl = topi[0][ra][a] * Nk + topi[1][ra][a];
                out[base + lane] = ea / sa;
                out[(size_t)W_ELEMS + base + lane] = (float)fl;
            }
            {
                const int bc = bc0 + rb;
                const size_t base = ((size_t)bc * Hh + h) * TK;
                const int a = wpb >> 5;
                const int fl = topi[0][rb][a] * Nk + topi[1][rb][a];
                out[base + lane] = eb / sb;
                out[(size_t)W_ELEMS + base + lane] = (float)fl;
            }
        }
    }
}

extern "C" void kernel_launch(void* const* d_in, const int* in_sizes, int n_in,
                              void* d_out, int out_size, void* d_ws, size_t ws_size,
                              hipStream_t stream)
{
    const float* query = (const float*)d_in[0];
    const float* keyl  = (const float*)d_in[1];
    const float* keyr  = (const float*)d_in[2];
    float* out = (float*)d_out;
    pk_kernel<<<dim3(8192), dim3(NT), 0, stream>>>(query, keyl, keyr, out);
}